// Round 2
// baseline (1496.836 us; speedup 1.0000x reference)
//
#include <hip/hip_runtime.h>

#define N_ROWS 131072
#define K_CODES 1024
#define D_DIM 128
// Flag threshold on fp32 pre-quantized gap. Needed: 2 roundings/code at
// ulp(~128)=1.53e-5 -> 3.1e-5 max reorder distance, + fp32 scoring error
// ~2e-7. 1e-4 gives 3x safety; flags ~2.5% of rows.
#define MARGIN 1.0e-4f

// ws layout (bytes):
//   0       : unsigned refine_count            (zeroed by memset, 1 KB region)
//   1024    : float  n2[K_CODES]               (4 KB)  -- np-pairwise-exact fp32
//   8192    : unsigned best_idx[N_ROWS]        (512 KB)
//   532480  : unsigned refine_list[N_ROWS]     (512 KB)
//   1056768 : double partials[1024]            (8 KB)

// numpy pairwise_sum (n=128): 8 accumulators over stride-8, sequential 16 terms
// each, then ((r0+r1)+(r2+r3))+((r4+r5)+(r6+r7)). __f*_rn blocks fp contraction
// so each square and each add gets its own fp32 rounding, like numpy.
__device__ __forceinline__ float np_sumsq_128(const float* __restrict__ p) {
    float r[8];
    #pragma unroll
    for (int j = 0; j < 8; ++j) r[j] = __fmul_rn(p[j], p[j]);
    #pragma unroll
    for (int i = 8; i < 128; i += 8)
        #pragma unroll
        for (int j = 0; j < 8; ++j)
            r[j] = __fadd_rn(r[j], __fmul_rn(p[i + j], p[i + j]));
    float t01 = __fadd_rn(r[0], r[1]), t23 = __fadd_rn(r[2], r[3]);
    float t45 = __fadd_rn(r[4], r[5]), t67 = __fadd_rn(r[6], r[7]);
    return __fadd_rn(__fadd_rn(t01, t23), __fadd_rn(t45, t67));
}

// ---------------- kernel 1: codebook squared norms (np-exact) ----------------
__global__ void vq_n2(const float* __restrict__ cb, float* __restrict__ n2) {
    int code = blockIdx.x * 256 + threadIdx.x;   // grid = 4 blocks
    n2[code] = np_sumsq_128(cb + (size_t)code * D_DIM);
}

// ---------------- kernel 2: main scoring + argmin(top2) ----------------
// One lane per row; X row in VGPRs; codebook addresses block-uniform.
// Scores are |e|^2 - 2 x.e (A omitted: constant per row, irrelevant for gaps).
__launch_bounds__(256, 2)
__global__ void vq_main(const float* __restrict__ x, const float* __restrict__ cb,
                        const float* __restrict__ n2, unsigned* __restrict__ best_idx,
                        unsigned* __restrict__ refine_list, unsigned* __restrict__ refine_count) {
    const int row = blockIdx.x * 256 + threadIdx.x;

    float xr[D_DIM];
    const float4* xrow = (const float4*)(x + (size_t)row * D_DIM);
    #pragma unroll
    for (int i = 0; i < D_DIM / 4; ++i) {
        float4 v = xrow[i];
        xr[4 * i + 0] = v.x; xr[4 * i + 1] = v.y;
        xr[4 * i + 2] = v.z; xr[4 * i + 3] = v.w;
    }

    float b1 = 3.0e38f, b2 = 3.0e38f;
    unsigned i1 = 0;

    for (int g = 0; g < K_CODES / 8; ++g) {          // 8 codes per iteration
        const float* w = cb + (size_t)g * 8 * D_DIM; // block-uniform pointer
        float a0 = 0.f, a1 = 0.f, a2 = 0.f, a3 = 0.f;
        float a4 = 0.f, a5 = 0.f, a6 = 0.f, a7 = 0.f;
        #pragma unroll
        for (int d = 0; d < D_DIM; d += 4) {
            float4 w0 = *(const float4*)(w + 0 * D_DIM + d);
            float4 w1 = *(const float4*)(w + 1 * D_DIM + d);
            float4 w2 = *(const float4*)(w + 2 * D_DIM + d);
            float4 w3 = *(const float4*)(w + 3 * D_DIM + d);
            float4 w4 = *(const float4*)(w + 4 * D_DIM + d);
            float4 w5 = *(const float4*)(w + 5 * D_DIM + d);
            float4 w6 = *(const float4*)(w + 6 * D_DIM + d);
            float4 w7 = *(const float4*)(w + 7 * D_DIM + d);
            a0 = fmaf(xr[d], w0.x, a0); a0 = fmaf(xr[d+1], w0.y, a0); a0 = fmaf(xr[d+2], w0.z, a0); a0 = fmaf(xr[d+3], w0.w, a0);
            a1 = fmaf(xr[d], w1.x, a1); a1 = fmaf(xr[d+1], w1.y, a1); a1 = fmaf(xr[d+2], w1.z, a1); a1 = fmaf(xr[d+3], w1.w, a1);
            a2 = fmaf(xr[d], w2.x, a2); a2 = fmaf(xr[d+1], w2.y, a2); a2 = fmaf(xr[d+2], w2.z, a2); a2 = fmaf(xr[d+3], w2.w, a2);
            a3 = fmaf(xr[d], w3.x, a3); a3 = fmaf(xr[d+1], w3.y, a3); a3 = fmaf(xr[d+2], w3.z, a3); a3 = fmaf(xr[d+3], w3.w, a3);
            a4 = fmaf(xr[d], w4.x, a4); a4 = fmaf(xr[d+1], w4.y, a4); a4 = fmaf(xr[d+2], w4.z, a4); a4 = fmaf(xr[d+3], w4.w, a4);
            a5 = fmaf(xr[d], w5.x, a5); a5 = fmaf(xr[d+1], w5.y, a5); a5 = fmaf(xr[d+2], w5.z, a5); a5 = fmaf(xr[d+3], w5.w, a5);
            a6 = fmaf(xr[d], w6.x, a6); a6 = fmaf(xr[d+1], w6.y, a6); a6 = fmaf(xr[d+2], w6.z, a6); a6 = fmaf(xr[d+3], w6.w, a6);
            a7 = fmaf(xr[d], w7.x, a7); a7 = fmaf(xr[d+1], w7.y, a7); a7 = fmaf(xr[d+2], w7.z, a7); a7 = fmaf(xr[d+3], w7.w, a7);
        }
        const float* nn = n2 + g * 8;  // uniform -> s_load
        float s; bool lt;
        s = fmaf(-2.f, a0, nn[0]); lt = s < b1; b2 = lt ? b1 : fminf(b2, s); i1 = lt ? (unsigned)(8*g+0) : i1; b1 = lt ? s : b1;
        s = fmaf(-2.f, a1, nn[1]); lt = s < b1; b2 = lt ? b1 : fminf(b2, s); i1 = lt ? (unsigned)(8*g+1) : i1; b1 = lt ? s : b1;
        s = fmaf(-2.f, a2, nn[2]); lt = s < b1; b2 = lt ? b1 : fminf(b2, s); i1 = lt ? (unsigned)(8*g+2) : i1; b1 = lt ? s : b1;
        s = fmaf(-2.f, a3, nn[3]); lt = s < b1; b2 = lt ? b1 : fminf(b2, s); i1 = lt ? (unsigned)(8*g+3) : i1; b1 = lt ? s : b1;
        s = fmaf(-2.f, a4, nn[4]); lt = s < b1; b2 = lt ? b1 : fminf(b2, s); i1 = lt ? (unsigned)(8*g+4) : i1; b1 = lt ? s : b1;
        s = fmaf(-2.f, a5, nn[5]); lt = s < b1; b2 = lt ? b1 : fminf(b2, s); i1 = lt ? (unsigned)(8*g+5) : i1; b1 = lt ? s : b1;
        s = fmaf(-2.f, a6, nn[6]); lt = s < b1; b2 = lt ? b1 : fminf(b2, s); i1 = lt ? (unsigned)(8*g+6) : i1; b1 = lt ? s : b1;
        s = fmaf(-2.f, a7, nn[7]); lt = s < b1; b2 = lt ? b1 : fminf(b2, s); i1 = lt ? (unsigned)(8*g+7) : i1; b1 = lt ? s : b1;
    }

    best_idx[row] = i1;
    // Rows whose top-2 pre-quantized gap is under MARGIN can have their argmin
    // decided by the reference's fp32 |x|^2-offset quantization -> exact redo.
    if (b2 - b1 < MARGIN) {
        unsigned p = atomicAdd(refine_count, 1u);
        refine_list[p] = (unsigned)row;
    }
}

// ---------------- kernel 3: quantization-exact rescan of near-tie rows -------
// Replicates np: d = fp32( fp32(A + B_c) - 2*fp32(x.e_c) ), argmin first-index.
// One wave per flagged row; lane-blocked codes so lower lane = lower indices.
__global__ void vq_refine(const float* __restrict__ x, const float* __restrict__ cb,
                          const float* __restrict__ n2,
                          const unsigned* __restrict__ refine_count,
                          const unsigned* __restrict__ refine_list,
                          unsigned* __restrict__ best_idx) {
    int lane = threadIdx.x & 63;
    unsigned gw = blockIdx.x * 4 + (threadIdx.x >> 6);
    unsigned n = *refine_count;
    for (unsigned wi = gw; wi < n; wi += gridDim.x * 4) {
        unsigned row = refine_list[wi];
        const float* xrow = x + (size_t)row * D_DIM;
        float A = np_sumsq_128(xrow);              // redundant per lane, cheap
        float best = 3.0e38f; unsigned bi = 0;
        #pragma unroll 1
        for (int j = 0; j < K_CODES / 64; ++j) {
            unsigned c = (unsigned)lane * (K_CODES / 64) + j;
            const float* e = cb + (size_t)c * D_DIM;
            double dotd = 0.0;
            for (int d = 0; d < D_DIM; ++d)
                dotd = fma((double)e[d], (double)xrow[d], dotd);
            float M  = (float)dotd;                // one fp32 rounding, like sgemm output
            float t1 = __fadd_rn(A, n2[c]);        // fp32(A + B_c)
            float dq = __fsub_rn(t1, 2.0f * M);    // fp32(t1 - 2M); 2M exact
            if (dq < best) { best = dq; bi = c; }  // strict < keeps first index
        }
        #pragma unroll
        for (int m = 1; m < 64; m <<= 1) {
            float    ob = __shfl_xor(best, m);
            unsigned oi = __shfl_xor(bi, m);
            if (ob < best || (ob == best && oi < bi)) { best = ob; bi = oi; }
        }
        if (lane == 0) best_idx[row] = bi;
    }
}

// ---------------- kernel 4: gather + straight-through + loss partials --------
__global__ void vq_out(const float* __restrict__ x, const float* __restrict__ cb,
                       const unsigned* __restrict__ best_idx, float* __restrict__ out,
                       double* __restrict__ partials) {
    const int t = threadIdx.x;
    const int rloc = t >> 5;       // 8 rows per block-iteration
    const int q = t & 31;          // 32 float4 per row
    double lsum = 0.0;
    for (int it = 0; it < N_ROWS / (1024 * 8); ++it) {
        int row = it * (1024 * 8) + blockIdx.x * 8 + rloc;
        unsigned idx = best_idx[row];
        float4 xv = ((const float4*)x)[(size_t)row * 32 + q];
        float4 ev = ((const float4*)cb)[(size_t)idx * 32 + q];
        float dx = ev.x - xv.x, dy = ev.y - xv.y, dz = ev.z - xv.z, dw = ev.w - xv.w;
        float4 o;
        o.x = xv.x + dx; o.y = xv.y + dy; o.z = xv.z + dz; o.w = xv.w + dw;  // x + (q - x)
        ((float4*)out)[(size_t)row * 32 + q] = o;
        lsum += (double)dx * dx + (double)dy * dy + (double)dz * dz + (double)dw * dw;
        if (q == 0) out[(size_t)N_ROWS * D_DIM + 1 + row] = (float)idx;
    }
    #pragma unroll
    for (int m = 32; m >= 1; m >>= 1) lsum += __shfl_xor(lsum, m);
    __shared__ double wsum[4];
    if ((t & 63) == 0) wsum[t >> 6] = lsum;
    __syncthreads();
    if (t == 0) partials[blockIdx.x] = wsum[0] + wsum[1] + wsum[2] + wsum[3];
}

// ---------------- kernel 5: finalize loss ----------------
__global__ void vq_fin(const double* __restrict__ partials, float* __restrict__ out) {
    int t = threadIdx.x;
    double s = partials[t] + partials[t + 256] + partials[t + 512] + partials[t + 768];
    #pragma unroll
    for (int m = 32; m >= 1; m >>= 1) s += __shfl_xor(s, m);
    __shared__ double wsum[4];
    if ((t & 63) == 0) wsum[t >> 6] = s;
    __syncthreads();
    if (t == 0) {
        double total = wsum[0] + wsum[1] + wsum[2] + wsum[3];
        // vq_loss = q_loss + 0.25*e_loss; both equal mean((q-x)^2) forward
        out[(size_t)N_ROWS * D_DIM] = (float)(1.25 * total / ((double)N_ROWS * D_DIM));
    }
}

extern "C" void kernel_launch(void* const* d_in, const int* in_sizes, int n_in,
                              void* d_out, int out_size, void* d_ws, size_t ws_size,
                              hipStream_t stream) {
    const float* x  = (const float*)d_in[0];
    const float* cb = (const float*)d_in[1];
    float* out = (float*)d_out;
    char* ws = (char*)d_ws;

    unsigned* refine_count = (unsigned*)ws;
    float*    n2           = (float*)(ws + 1024);
    unsigned* best_idx     = (unsigned*)(ws + 8192);
    unsigned* refine_list  = (unsigned*)(ws + 8192 + 524288);
    double*   partials     = (double*)(ws + 8192 + 2 * 524288);

    hipMemsetAsync(ws, 0, 1024, stream);  // refine_count = 0
    vq_n2    <<<K_CODES / 256, 256, 0, stream>>>(cb, n2);
    vq_main  <<<N_ROWS / 256, 256, 0, stream>>>(x, cb, n2, best_idx, refine_list, refine_count);
    vq_refine<<<256, 256, 0, stream>>>(x, cb, n2, refine_count, refine_list, best_idx);
    vq_out   <<<1024, 256, 0, stream>>>(x, cb, best_idx, out, partials);
    vq_fin   <<<1, 256, 0, stream>>>(partials, out);
}

// Round 3
// 591.555 us; speedup vs baseline: 2.5303x; 2.5303x over previous
//
#include <hip/hip_runtime.h>

#define N_ROWS 131072
#define K_CODES 1024
#define D_DIM 128
// Flag threshold on pre-quantized top-2 gap (see round-1/2 analysis):
// quantization reorder needs 3.1e-5, scoring error ~1e-7 -> 1e-4 = 3x safety.
#define MARGIN 1.0e-4f

typedef __attribute__((ext_vector_type(8)))  short short8;   // 8 bf16, 4 VGPRs
typedef __attribute__((ext_vector_type(4)))  float f32x4;

// ws layout (bytes):
//   0       : unsigned refine_count            (1 KB region, memset to 0)
//   1024    : float  n2[K_CODES]               (4 KB)  np-pairwise-exact fp32
//   8192    : unsigned best_idx[N_ROWS]        (512 KB)
//   532480  : unsigned refine_list[N_ROWS]     (512 KB)
//   1056768 : double partials[1024]            (8 KB)
//   1064960 : ushort EH[K][D]                  (256 KB)  bf16 hi of codebook
//   1327104 : ushort EL[K][D]                  (256 KB)  bf16 lo of codebook
// total: 1,589,248 B

// ---- bf16 round-to-nearest-even split helpers (manual, type-stable) ----
__device__ __forceinline__ unsigned short bf16_rn(float f) {
    unsigned u = __float_as_uint(f);
    unsigned r = u + 0x7fffu + ((u >> 16) & 1u);
    return (unsigned short)(r >> 16);
}
__device__ __forceinline__ float bf16_to_f(unsigned short h) {
    return __uint_as_float(((unsigned)h) << 16);
}

// numpy pairwise_sum (n=128) replica for |.|^2 — needed by refine path.
__device__ __forceinline__ float np_sumsq_128(const float* __restrict__ p) {
    float r[8];
    #pragma unroll
    for (int j = 0; j < 8; ++j) r[j] = __fmul_rn(p[j], p[j]);
    #pragma unroll
    for (int i = 8; i < 128; i += 8)
        #pragma unroll
        for (int j = 0; j < 8; ++j)
            r[j] = __fadd_rn(r[j], __fmul_rn(p[i + j], p[i + j]));
    float t01 = __fadd_rn(r[0], r[1]), t23 = __fadd_rn(r[2], r[3]);
    float t45 = __fadd_rn(r[4], r[5]), t67 = __fadd_rn(r[6], r[7]);
    return __fadd_rn(__fadd_rn(t01, t23), __fadd_rn(t45, t67));
}

// ---------------- kernel 1: codebook squared norms (np-exact) ----------------
__global__ void vq_n2(const float* __restrict__ cb, float* __restrict__ n2) {
    int code = blockIdx.x * 256 + threadIdx.x;   // grid = 4 blocks
    n2[code] = np_sumsq_128(cb + (size_t)code * D_DIM);
}

// ---------------- kernel 1b: split codebook into bf16 hi/lo ----------------
__global__ void vq_split(const float* __restrict__ cb, unsigned short* __restrict__ EH,
                         unsigned short* __restrict__ EL) {
    int i = blockIdx.x * 256 + threadIdx.x;      // grid = K*D/256 = 512 blocks
    float e = cb[i];
    unsigned short h = bf16_rn(e);
    float fl = e - bf16_to_f(h);                 // exact (Sterbenz)
    EH[i] = h;
    EL[i] = bf16_rn(fl);
}

// ---------------- kernel 2: MFMA scoring + per-row top-2 argmin ----------------
// Codes on M, rows on N. D tile 16(codes) x 16(rows); C/D: col=lane&15 -> x-row
// (FIXED per lane), row=quad*4+reg -> code. Each wave: 4 row-tiles (64 rows),
// all 1024 codes in 64 code-tiles. Scores = n2[c] - 2*dot (|x|^2 const/row).
// dot via bf16 split: eh*xh + eh*xl + el*xh, fp32 MFMA accum (err ~1e-7).
__launch_bounds__(256, 2)
__global__ void vq_mfma(const float* __restrict__ x,
                        const unsigned short* __restrict__ EH,
                        const unsigned short* __restrict__ EL,
                        const float* __restrict__ n2,
                        unsigned* __restrict__ best_idx,
                        unsigned* __restrict__ refine_list,
                        unsigned* __restrict__ refine_count) {
    const int lane = threadIdx.x & 63;
    const int wid  = threadIdx.x >> 6;
    const int q    = lane >> 4;          // quad 0..3
    const int col  = lane & 15;
    const int rbase = blockIdx.x * 256 + wid * 64;

    // ---- B operand (x rows), resident for the whole kernel ----
    // B[k][n]: n = lane&15 = row-in-tile, k = quad*8 + j.
    short8 xh[4][4], xl[4][4];           // [row-tile][kstep] — 128 VGPRs
    #pragma unroll
    for (int r = 0; r < 4; ++r) {
        const float* xrow = x + (size_t)(rbase + 16 * r + col) * D_DIM;
        #pragma unroll
        for (int k = 0; k < 4; ++k) {
            const float* p = xrow + k * 32 + q * 8;
            f32x4 v0 = *(const f32x4*)p;
            f32x4 v1 = *(const f32x4*)(p + 4);
            float f[8] = {v0.x, v0.y, v0.z, v0.w, v1.x, v1.y, v1.z, v1.w};
            short8 h, l;
            #pragma unroll
            for (int j = 0; j < 8; ++j) {
                unsigned short hb = bf16_rn(f[j]);
                float fl = f[j] - bf16_to_f(hb);
                h[j] = (short)hb;
                l[j] = (short)bf16_rn(fl);
            }
            xh[r][k] = h; xl[r][k] = l;
        }
    }

    float b1[4] = {3.0e38f, 3.0e38f, 3.0e38f, 3.0e38f};
    float b2[4] = {3.0e38f, 3.0e38f, 3.0e38f, 3.0e38f};
    unsigned i1[4] = {0, 0, 0, 0};

    for (int ct = 0; ct < K_CODES / 16; ++ct) {
        // A operand (codes): A[m][k]: m = lane&15 = code-in-tile, k = quad*8+j
        const unsigned short* ph = EH + ((size_t)(ct * 16 + col)) * D_DIM + q * 8;
        const unsigned short* pl = EL + ((size_t)(ct * 16 + col)) * D_DIM + q * 8;

        f32x4 acc[4];
        #pragma unroll
        for (int r = 0; r < 4; ++r) acc[r] = (f32x4){0.f, 0.f, 0.f, 0.f};

        #pragma unroll
        for (int k = 0; k < 4; ++k) {
            short8 eh = *(const short8*)(ph + k * 32);
            short8 el = *(const short8*)(pl + k * 32);
            #pragma unroll
            for (int r = 0; r < 4; ++r) {
                acc[r] = __builtin_amdgcn_mfma_f32_16x16x32_bf16(eh, xh[r][k], acc[r], 0, 0, 0);
                acc[r] = __builtin_amdgcn_mfma_f32_16x16x32_bf16(eh, xl[r][k], acc[r], 0, 0, 0);
                acc[r] = __builtin_amdgcn_mfma_f32_16x16x32_bf16(el, xh[r][k], acc[r], 0, 0, 0);
            }
        }

        // epilogue: lane's 4 scores per row-tile are codes ct*16 + q*4 + reg
        f32x4 nn = *(const f32x4*)(n2 + ct * 16 + q * 4);
        #pragma unroll
        for (int r = 0; r < 4; ++r) {
            #pragma unroll
            for (int g = 0; g < 4; ++g) {
                float v = fmaf(-2.0f, acc[r][g], nn[g]);
                unsigned c = (unsigned)(ct * 16 + q * 4 + g);
                bool lt = v < b1[r];
                b2[r] = lt ? b1[r] : fminf(b2[r], v);
                i1[r] = lt ? c : i1[r];
                b1[r] = lt ? v : b1[r];
            }
        }
    }

    // merge top-2 across the 4 quads (lanes L, L+16, L+32, L+48 share a row)
    #pragma unroll
    for (int r = 0; r < 4; ++r) {
        #pragma unroll
        for (int m = 16; m <= 32; m <<= 1) {
            float    ob1 = __shfl_xor(b1[r], m);
            float    ob2 = __shfl_xor(b2[r], m);
            unsigned oi  = __shfl_xor(i1[r], m);
            bool other = (ob1 < b1[r]) || (ob1 == b1[r] && oi < i1[r]);
            float nb2 = other ? fminf(ob2, b1[r]) : fminf(b2[r], ob1);
            b1[r] = other ? ob1 : b1[r];
            i1[r] = other ? oi  : i1[r];
            b2[r] = nb2;
        }
        if (lane < 16) {
            int row = rbase + 16 * r + lane;
            best_idx[row] = i1[r];
            if (b2[r] - b1[r] < MARGIN) {
                unsigned p = atomicAdd(refine_count, 1u);
                refine_list[p] = (unsigned)row;
            }
        }
    }
}

// ---------------- kernel 3: quantization-exact rescan of near-tie rows -------
__global__ void vq_refine(const float* __restrict__ x, const float* __restrict__ cb,
                          const float* __restrict__ n2,
                          const unsigned* __restrict__ refine_count,
                          const unsigned* __restrict__ refine_list,
                          unsigned* __restrict__ best_idx) {
    int lane = threadIdx.x & 63;
    unsigned gw = blockIdx.x * 4 + (threadIdx.x >> 6);
    unsigned n = *refine_count;
    for (unsigned wi = gw; wi < n; wi += gridDim.x * 4) {
        unsigned row = refine_list[wi];
        const float* xrow = x + (size_t)row * D_DIM;
        float A = np_sumsq_128(xrow);
        float best = 3.0e38f; unsigned bi = 0;
        #pragma unroll 1
        for (int j = 0; j < K_CODES / 64; ++j) {
            unsigned c = (unsigned)lane * (K_CODES / 64) + j;
            const float* e = cb + (size_t)c * D_DIM;
            double dotd = 0.0;
            for (int d = 0; d < D_DIM; ++d)
                dotd = fma((double)e[d], (double)xrow[d], dotd);
            float M  = (float)dotd;                // one fp32 rounding (sgemm-like)
            float t1 = __fadd_rn(A, n2[c]);        // fp32(A + B_c)
            float dq = __fsub_rn(t1, 2.0f * M);    // fp32(t1 - 2M)
            if (dq < best) { best = dq; bi = c; }  // strict < keeps first index
        }
        #pragma unroll
        for (int m = 1; m < 64; m <<= 1) {
            float    ob = __shfl_xor(best, m);
            unsigned oi = __shfl_xor(bi, m);
            if (ob < best || (ob == best && oi < bi)) { best = ob; bi = oi; }
        }
        if (lane == 0) best_idx[row] = bi;
    }
}

// ---------------- kernel 4: gather + straight-through + loss partials --------
__global__ void vq_out(const float* __restrict__ x, const float* __restrict__ cb,
                       const unsigned* __restrict__ best_idx, float* __restrict__ out,
                       double* __restrict__ partials) {
    const int t = threadIdx.x;
    const int rloc = t >> 5;       // 8 rows per block-iteration
    const int q = t & 31;          // 32 float4 per row
    double lsum = 0.0;
    for (int it = 0; it < N_ROWS / (1024 * 8); ++it) {
        int row = it * (1024 * 8) + blockIdx.x * 8 + rloc;
        unsigned idx = best_idx[row];
        float4 xv = ((const float4*)x)[(size_t)row * 32 + q];
        float4 ev = ((const float4*)cb)[(size_t)idx * 32 + q];
        float dx = ev.x - xv.x, dy = ev.y - xv.y, dz = ev.z - xv.z, dw = ev.w - xv.w;
        float4 o;
        o.x = xv.x + dx; o.y = xv.y + dy; o.z = xv.z + dz; o.w = xv.w + dw;
        ((float4*)out)[(size_t)row * 32 + q] = o;
        lsum += (double)dx * dx + (double)dy * dy + (double)dz * dz + (double)dw * dw;
        if (q == 0) out[(size_t)N_ROWS * D_DIM + 1 + row] = (float)idx;
    }
    #pragma unroll
    for (int m = 32; m >= 1; m >>= 1) lsum += __shfl_xor(lsum, m);
    __shared__ double wsum[4];
    if ((t & 63) == 0) wsum[t >> 6] = lsum;
    __syncthreads();
    if (t == 0) partials[blockIdx.x] = wsum[0] + wsum[1] + wsum[2] + wsum[3];
}

// ---------------- kernel 5: finalize loss ----------------
__global__ void vq_fin(const double* __restrict__ partials, float* __restrict__ out) {
    int t = threadIdx.x;
    double s = partials[t] + partials[t + 256] + partials[t + 512] + partials[t + 768];
    #pragma unroll
    for (int m = 32; m >= 1; m >>= 1) s += __shfl_xor(s, m);
    __shared__ double wsum[4];
    if ((t & 63) == 0) wsum[t >> 6] = s;
    __syncthreads();
    if (t == 0) {
        double total = wsum[0] + wsum[1] + wsum[2] + wsum[3];
        out[(size_t)N_ROWS * D_DIM] = (float)(1.25 * total / ((double)N_ROWS * D_DIM));
    }
}

extern "C" void kernel_launch(void* const* d_in, const int* in_sizes, int n_in,
                              void* d_out, int out_size, void* d_ws, size_t ws_size,
                              hipStream_t stream) {
    const float* x  = (const float*)d_in[0];
    const float* cb = (const float*)d_in[1];
    float* out = (float*)d_out;
    char* ws = (char*)d_ws;

    unsigned*       refine_count = (unsigned*)ws;
    float*          n2           = (float*)(ws + 1024);
    unsigned*       best_idx     = (unsigned*)(ws + 8192);
    unsigned*       refine_list  = (unsigned*)(ws + 8192 + 524288);
    double*         partials     = (double*)(ws + 8192 + 2 * 524288);
    unsigned short* EH           = (unsigned short*)(ws + 1064960);
    unsigned short* EL           = (unsigned short*)(ws + 1327104);

    hipMemsetAsync(ws, 0, 1024, stream);  // refine_count = 0
    vq_n2    <<<K_CODES / 256, 256, 0, stream>>>(cb, n2);
    vq_split <<<K_CODES * D_DIM / 256, 256, 0, stream>>>(cb, EH, EL);
    vq_mfma  <<<N_ROWS / 256, 256, 0, stream>>>(x, EH, EL, n2, best_idx, refine_list, refine_count);
    vq_refine<<<256, 256, 0, stream>>>(x, cb, n2, refine_count, refine_list, best_idx);
    vq_out   <<<1024, 256, 0, stream>>>(x, cb, best_idx, out, partials);
    vq_fin   <<<1, 256, 0, stream>>>(partials, out);
}

// Round 4
// 516.482 us; speedup vs baseline: 2.8981x; 1.1454x over previous
//
#include <hip/hip_runtime.h>

#define N_ROWS 131072
#define K_CODES 1024
#define D_DIM 128
// Flag threshold on pre-quantized top-2 gap: quantization can reorder codes
// within 2*0.5ulp(~128)=3.2e-5; mfma scoring err ~3e-7. 5e-5 = 1.5x safety.
#define MARGIN 5.0e-5f
// Candidate threshold inside refine (vs refine's own fp32 min, err ~3e-8).
#define CAND_MARGIN 4.0e-5f

typedef __attribute__((ext_vector_type(8)))  short short8;   // 8 bf16, 4 VGPRs
typedef __attribute__((ext_vector_type(4)))  float f32x4;

// ws layout (bytes):
//   0       : unsigned refine_count            (1 KB region, memset to 0)
//   1024    : float  n2[K_CODES]               (4 KB)  np-pairwise-exact fp32
//   8192    : unsigned best_idx[N_ROWS]        (512 KB)
//   532480  : unsigned refine_list[N_ROWS]     (512 KB)
//   1056768 : double partials[1024]            (8 KB)
//   1064960 : ushort EH[K][D]                  (256 KB)  bf16 hi of codebook
//   1327104 : ushort EL[K][D]                  (256 KB)  bf16 lo of codebook
// total: 1,589,248 B

// ---- bf16 round-to-nearest-even split helpers ----
__device__ __forceinline__ unsigned short bf16_rn(float f) {
    unsigned u = __float_as_uint(f);
    unsigned r = u + 0x7fffu + ((u >> 16) & 1u);
    return (unsigned short)(r >> 16);
}
__device__ __forceinline__ float bf16_to_f(unsigned short h) {
    return __uint_as_float(((unsigned)h) << 16);
}

// numpy pairwise_sum (n=128) replica: 8 accumulators stride-8, then pairwise
// combine. __f*_rn blocks contraction so every op gets its own fp32 rounding.
__device__ __forceinline__ float np_sumsq_128(const float* __restrict__ p) {
    float r[8];
    #pragma unroll
    for (int j = 0; j < 8; ++j) r[j] = __fmul_rn(p[j], p[j]);
    #pragma unroll
    for (int i = 8; i < 128; i += 8)
        #pragma unroll
        for (int j = 0; j < 8; ++j)
            r[j] = __fadd_rn(r[j], __fmul_rn(p[i + j], p[i + j]));
    float t01 = __fadd_rn(r[0], r[1]), t23 = __fadd_rn(r[2], r[3]);
    float t45 = __fadd_rn(r[4], r[5]), t67 = __fadd_rn(r[6], r[7]);
    return __fadd_rn(__fadd_rn(t01, t23), __fadd_rn(t45, t67));
}

// fp32 score of code c vs register-resident row xr (deterministic helper:
// both refine passes call this, so selection is self-consistent).
__device__ __forceinline__ float score_f32(const float* __restrict__ e,
                                           const float* __restrict__ xr, float nn) {
    float a0 = 0.f, a1 = 0.f, a2 = 0.f, a3 = 0.f;
    #pragma unroll
    for (int d = 0; d < D_DIM; d += 4) {
        f32x4 ev = *(const f32x4*)(e + d);
        a0 = fmaf(xr[d + 0], ev.x, a0);
        a1 = fmaf(xr[d + 1], ev.y, a1);
        a2 = fmaf(xr[d + 2], ev.z, a2);
        a3 = fmaf(xr[d + 3], ev.w, a3);
    }
    return fmaf(-2.f, (a0 + a1) + (a2 + a3), nn);
}

// ---------------- kernel 1: codebook squared norms (np-exact) ----------------
__global__ void vq_n2(const float* __restrict__ cb, float* __restrict__ n2) {
    int code = blockIdx.x * 256 + threadIdx.x;   // grid = 4 blocks
    n2[code] = np_sumsq_128(cb + (size_t)code * D_DIM);
}

// ---------------- kernel 1b: split codebook into bf16 hi/lo ----------------
__global__ void vq_split(const float* __restrict__ cb, unsigned short* __restrict__ EH,
                         unsigned short* __restrict__ EL) {
    int i = blockIdx.x * 256 + threadIdx.x;      // grid = 512 blocks
    float e = cb[i];
    unsigned short h = bf16_rn(e);
    float fl = e - bf16_to_f(h);                 // exact (Sterbenz)
    EH[i] = h;
    EL[i] = bf16_rn(fl);
}

// ---------------- kernel 2: MFMA scoring + per-row top-2 argmin ----------------
// Codes on M, rows on N. C/D: col=lane&15 -> x-row (fixed per lane),
// row=quad*4+reg -> code. Each wave: 64 rows x all 1024 codes.
// dot via bf16 split: eh*xh + eh*xl + el*xh, fp32 MFMA accum (err ~3e-7).
__launch_bounds__(256, 2)
__global__ void vq_mfma(const float* __restrict__ x,
                        const unsigned short* __restrict__ EH,
                        const unsigned short* __restrict__ EL,
                        const float* __restrict__ n2,
                        unsigned* __restrict__ best_idx,
                        unsigned* __restrict__ refine_list,
                        unsigned* __restrict__ refine_count) {
    const int lane = threadIdx.x & 63;
    const int wid  = threadIdx.x >> 6;
    const int q    = lane >> 4;          // quad 0..3
    const int col  = lane & 15;
    const int rbase = blockIdx.x * 256 + wid * 64;

    // B operand (x rows), resident: B[k][n]: n = col = row-in-tile, k = q*8+j.
    short8 xh[4][4], xl[4][4];           // [row-tile][kstep] — 128 VGPRs
    #pragma unroll
    for (int r = 0; r < 4; ++r) {
        const float* xrow = x + (size_t)(rbase + 16 * r + col) * D_DIM;
        #pragma unroll
        for (int k = 0; k < 4; ++k) {
            const float* p = xrow + k * 32 + q * 8;
            f32x4 v0 = *(const f32x4*)p;
            f32x4 v1 = *(const f32x4*)(p + 4);
            float f[8] = {v0.x, v0.y, v0.z, v0.w, v1.x, v1.y, v1.z, v1.w};
            short8 h, l;
            #pragma unroll
            for (int j = 0; j < 8; ++j) {
                unsigned short hb = bf16_rn(f[j]);
                float fl = f[j] - bf16_to_f(hb);
                h[j] = (short)hb;
                l[j] = (short)bf16_rn(fl);
            }
            xh[r][k] = h; xl[r][k] = l;
        }
    }

    float b1[4] = {3.0e38f, 3.0e38f, 3.0e38f, 3.0e38f};
    float b2[4] = {3.0e38f, 3.0e38f, 3.0e38f, 3.0e38f};
    unsigned i1[4] = {0, 0, 0, 0};

    for (int ct = 0; ct < K_CODES / 16; ++ct) {
        const unsigned short* ph = EH + ((size_t)(ct * 16 + col)) * D_DIM + q * 8;
        const unsigned short* pl = EL + ((size_t)(ct * 16 + col)) * D_DIM + q * 8;

        f32x4 acc[4];
        #pragma unroll
        for (int r = 0; r < 4; ++r) acc[r] = (f32x4){0.f, 0.f, 0.f, 0.f};

        #pragma unroll
        for (int k = 0; k < 4; ++k) {
            short8 eh = *(const short8*)(ph + k * 32);
            short8 el = *(const short8*)(pl + k * 32);
            #pragma unroll
            for (int r = 0; r < 4; ++r) {
                acc[r] = __builtin_amdgcn_mfma_f32_16x16x32_bf16(eh, xh[r][k], acc[r], 0, 0, 0);
                acc[r] = __builtin_amdgcn_mfma_f32_16x16x32_bf16(eh, xl[r][k], acc[r], 0, 0, 0);
                acc[r] = __builtin_amdgcn_mfma_f32_16x16x32_bf16(el, xh[r][k], acc[r], 0, 0, 0);
            }
        }

        f32x4 nn = *(const f32x4*)(n2 + ct * 16 + q * 4);
        #pragma unroll
        for (int r = 0; r < 4; ++r) {
            #pragma unroll
            for (int g = 0; g < 4; ++g) {
                float v = fmaf(-2.0f, acc[r][g], nn[g]);
                unsigned c = (unsigned)(ct * 16 + q * 4 + g);
                bool lt = v < b1[r];
                b2[r] = lt ? b1[r] : fminf(b2[r], v);
                i1[r] = lt ? c : i1[r];
                b1[r] = lt ? v : b1[r];
            }
        }
    }

    // merge top-2 across the 4 quads (lanes L, L+16, L+32, L+48 share a row)
    #pragma unroll
    for (int r = 0; r < 4; ++r) {
        #pragma unroll
        for (int m = 16; m <= 32; m <<= 1) {
            float    ob1 = __shfl_xor(b1[r], m);
            float    ob2 = __shfl_xor(b2[r], m);
            unsigned oi  = __shfl_xor(i1[r], m);
            bool other = (ob1 < b1[r]) || (ob1 == b1[r] && oi < i1[r]);
            float nb2 = other ? fminf(ob2, b1[r]) : fminf(b2[r], ob1);
            b1[r] = other ? ob1 : b1[r];
            i1[r] = other ? oi  : i1[r];
            b2[r] = nb2;
        }
        if (lane < 16) {
            int row = rbase + 16 * r + lane;
            best_idx[row] = i1[r];
            if (b2[r] - b1[r] < MARGIN) {
                unsigned p = atomicAdd(refine_count, 1u);
                refine_list[p] = (unsigned)row;
            }
        }
    }
}

// ---------------- kernel 3: candidate-sparse quantization-exact rescan -------
// Pass 1: fp32 scores (16 codes/lane, float4 loads) -> wave min b1w.
// Pass 2: recompute (identical helper); for codes within CAND_MARGIN of b1w
// (typically 2/row) compute np-quantized score d = fp32(fp32(A+B_c) - 2M),
// M = fp32(fp64 dot). Argmin with first-index ties.
__launch_bounds__(256, 1)
__global__ void vq_refine(const float* __restrict__ x, const float* __restrict__ cb,
                          const float* __restrict__ n2,
                          const unsigned* __restrict__ refine_count,
                          const unsigned* __restrict__ refine_list,
                          unsigned* __restrict__ best_idx) {
    const int lane = threadIdx.x & 63;
    const unsigned gw = blockIdx.x * 4 + (threadIdx.x >> 6);
    const unsigned n = *refine_count;
    for (unsigned wi = gw; wi < n; wi += 1024) {
        const unsigned row = refine_list[wi];
        const float* xrow = x + (size_t)row * D_DIM;

        float xr[D_DIM];                    // fully-unrolled accesses only
        #pragma unroll
        for (int i = 0; i < D_DIM / 4; ++i) {
            f32x4 v = ((const f32x4*)xrow)[i];
            xr[4 * i + 0] = v.x; xr[4 * i + 1] = v.y;
            xr[4 * i + 2] = v.z; xr[4 * i + 3] = v.w;
        }
        float A = np_sumsq_128(xr);         // np-exact |x|^2

        // pass 1: wave-wide fp32 min
        float smin = 3.0e38f;
        #pragma unroll 1
        for (int j = 0; j < K_CODES / 64; ++j) {
            unsigned c = (unsigned)lane * (K_CODES / 64) + j;
            smin = fminf(smin, score_f32(cb + (size_t)c * D_DIM, xr, n2[c]));
        }
        float b1w = smin;
        #pragma unroll
        for (int m = 1; m < 64; m <<= 1) b1w = fminf(b1w, __shfl_xor(b1w, m));

        // pass 2: quantized-exact eval of candidates only
        float bestq = 3.0e38f; unsigned bi = 0xffffffffu;
        #pragma unroll 1
        for (int j = 0; j < K_CODES / 64; ++j) {
            unsigned c = (unsigned)lane * (K_CODES / 64) + j;
            float s = score_f32(cb + (size_t)c * D_DIM, xr, n2[c]);
            if (s < b1w + CAND_MARGIN) {
                const float* e = cb + (size_t)c * D_DIM;
                double dotd = 0.0;
                #pragma unroll
                for (int d = 0; d < D_DIM; ++d)
                    dotd = fma((double)e[d], (double)xr[d], dotd);
                float M  = (float)dotd;            // one fp32 rounding (sgemm-like)
                float t1 = __fadd_rn(A, n2[c]);    // fp32(A + B_c)
                float dq = __fsub_rn(t1, 2.0f * M);
                if (dq < bestq) { bestq = dq; bi = c; }  // strict < = first index
            }
        }
        #pragma unroll
        for (int m = 1; m < 64; m <<= 1) {
            float    ob = __shfl_xor(bestq, m);
            unsigned oi = __shfl_xor(bi, m);
            if (ob < bestq || (ob == bestq && oi < bi)) { bestq = ob; bi = oi; }
        }
        if (lane == 0) best_idx[row] = bi;
    }
}

// ---------------- kernel 4: gather + straight-through + loss partials --------
__global__ void vq_out(const float* __restrict__ x, const float* __restrict__ cb,
                       const unsigned* __restrict__ best_idx, float* __restrict__ out,
                       double* __restrict__ partials) {
    const int t = threadIdx.x;
    const int rloc = t >> 5;
    const int q = t & 31;
    double lsum = 0.0;
    for (int it = 0; it < N_ROWS / (1024 * 8); ++it) {
        int row = it * (1024 * 8) + blockIdx.x * 8 + rloc;
        unsigned idx = best_idx[row];
        float4 xv = ((const float4*)x)[(size_t)row * 32 + q];
        float4 ev = ((const float4*)cb)[(size_t)idx * 32 + q];
        float dx = ev.x - xv.x, dy = ev.y - xv.y, dz = ev.z - xv.z, dw = ev.w - xv.w;
        float4 o;
        o.x = xv.x + dx; o.y = xv.y + dy; o.z = xv.z + dz; o.w = xv.w + dw;
        ((float4*)out)[(size_t)row * 32 + q] = o;
        lsum += (double)dx * dx + (double)dy * dy + (double)dz * dz + (double)dw * dw;
        if (q == 0) out[(size_t)N_ROWS * D_DIM + 1 + row] = (float)idx;
    }
    #pragma unroll
    for (int m = 32; m >= 1; m >>= 1) lsum += __shfl_xor(lsum, m);
    __shared__ double wsum[4];
    if ((t & 63) == 0) wsum[t >> 6] = lsum;
    __syncthreads();
    if (t == 0) partials[blockIdx.x] = wsum[0] + wsum[1] + wsum[2] + wsum[3];
}

// ---------------- kernel 5: finalize loss ----------------
__global__ void vq_fin(const double* __restrict__ partials, float* __restrict__ out) {
    int t = threadIdx.x;
    double s = partials[t] + partials[t + 256] + partials[t + 512] + partials[t + 768];
    #pragma unroll
    for (int m = 32; m >= 1; m >>= 1) s += __shfl_xor(s, m);
    __shared__ double wsum[4];
    if ((t & 63) == 0) wsum[t >> 6] = s;
    __syncthreads();
    if (t == 0) {
        double total = wsum[0] + wsum[1] + wsum[2] + wsum[3];
        out[(size_t)N_ROWS * D_DIM] = (float)(1.25 * total / ((double)N_ROWS * D_DIM));
    }
}

extern "C" void kernel_launch(void* const* d_in, const int* in_sizes, int n_in,
                              void* d_out, int out_size, void* d_ws, size_t ws_size,
                              hipStream_t stream) {
    const float* x  = (const float*)d_in[0];
    const float* cb = (const float*)d_in[1];
    float* out = (float*)d_out;
    char* ws = (char*)d_ws;

    unsigned*       refine_count = (unsigned*)ws;
    float*          n2           = (float*)(ws + 1024);
    unsigned*       best_idx     = (unsigned*)(ws + 8192);
    unsigned*       refine_list  = (unsigned*)(ws + 8192 + 524288);
    double*         partials     = (double*)(ws + 8192 + 2 * 524288);
    unsigned short* EH           = (unsigned short*)(ws + 1064960);
    unsigned short* EL           = (unsigned short*)(ws + 1327104);

    hipMemsetAsync(ws, 0, 1024, stream);  // refine_count = 0
    vq_n2    <<<K_CODES / 256, 256, 0, stream>>>(cb, n2);
    vq_split <<<K_CODES * D_DIM / 256, 256, 0, stream>>>(cb, EH, EL);
    vq_mfma  <<<N_ROWS / 256, 256, 0, stream>>>(x, EH, EL, n2, best_idx, refine_list, refine_count);
    vq_refine<<<256, 256, 0, stream>>>(x, cb, n2, refine_count, refine_list, best_idx);
    vq_out   <<<1024, 256, 0, stream>>>(x, cb, best_idx, out, partials);
    vq_fin   <<<1, 256, 0, stream>>>(partials, out);
}

// Round 5
// 362.232 us; speedup vs baseline: 4.1323x; 1.4258x over previous
//
#include <hip/hip_runtime.h>

#define N_ROWS 131072
#define K_CODES 1024
#define D_DIM 128
// Quantization of the reference's fp32 |x|^2-offset arithmetic can reorder
// codes whose pre-quantized score gap is < 2*0.5ulp(~128)=3.2e-5; mfma
// scoring error ~3e-7. MARGIN = 5e-5 gives ~1.5x safety.
#define MARGIN 5.0e-5f
// Candidate window inside the full rescan (vs its own fp32 min, err ~3e-8).
#define CAND_MARGIN 4.0e-5f

typedef __attribute__((ext_vector_type(8)))  short short8;   // 8 bf16, 4 VGPRs
typedef __attribute__((ext_vector_type(4)))  float f32x4;

// ws layout (bytes) — total 1,589,248:
//   0       : unsigned work_count              (1 KB region, memset to 0)
//   1024    : float  n2[K_CODES]               (4 KB)  np-pairwise-exact fp32
//   8192    : unsigned best_idx[N_ROWS]        (512 KB)
//   532480  : unsigned work_list[N_ROWS]       (512 KB)  row|i2<<17|full<<31
//   1056768 : double partials[1024]            (8 KB)
//   1064960 : ushort EH[K][D]                  (256 KB)  bf16 hi of codebook
//   1327104 : ushort EL[K][D]                  (256 KB)  bf16 lo of codebook

// ---- bf16 round-to-nearest-even split helpers ----
__device__ __forceinline__ unsigned short bf16_rn(float f) {
    unsigned u = __float_as_uint(f);
    unsigned r = u + 0x7fffu + ((u >> 16) & 1u);
    return (unsigned short)(r >> 16);
}
__device__ __forceinline__ float bf16_to_f(unsigned short h) {
    return __uint_as_float(((unsigned)h) << 16);
}

// numpy pairwise_sum (n=128) replica: 8 accumulators stride-8, then pairwise
// combine. __f*_rn blocks contraction so every op gets its own fp32 rounding.
__device__ __forceinline__ float np_sumsq_128(const float* __restrict__ p) {
    float r[8];
    #pragma unroll
    for (int j = 0; j < 8; ++j) r[j] = __fmul_rn(p[j], p[j]);
    #pragma unroll
    for (int i = 8; i < 128; i += 8)
        #pragma unroll
        for (int j = 0; j < 8; ++j)
            r[j] = __fadd_rn(r[j], __fmul_rn(p[i + j], p[i + j]));
    float t01 = __fadd_rn(r[0], r[1]), t23 = __fadd_rn(r[2], r[3]);
    float t45 = __fadd_rn(r[4], r[5]), t67 = __fadd_rn(r[6], r[7]);
    return __fadd_rn(__fadd_rn(t01, t23), __fadd_rn(t45, t67));
}

// fp32 score helper for the full-rescan path (self-consistent across passes).
__device__ __forceinline__ float score_f32(const float* __restrict__ e,
                                           const float* __restrict__ xr, float nn) {
    float a0 = 0.f, a1 = 0.f, a2 = 0.f, a3 = 0.f;
    #pragma unroll
    for (int d = 0; d < D_DIM; d += 4) {
        f32x4 ev = *(const f32x4*)(e + d);
        a0 = fmaf(xr[d + 0], ev.x, a0);
        a1 = fmaf(xr[d + 1], ev.y, a1);
        a2 = fmaf(xr[d + 2], ev.z, a2);
        a3 = fmaf(xr[d + 3], ev.w, a3);
    }
    return fmaf(-2.f, (a0 + a1) + (a2 + a3), nn);
}

// np-quantized score: d = fp32( fp32(A + B_c) - 2*fp32(fp64 x.e_c) ).
__device__ __forceinline__ float quant_score(const float* __restrict__ e,
                                             const float* __restrict__ xr,
                                             float A, float nn) {
    double dotd = 0.0;
    #pragma unroll
    for (int d = 0; d < D_DIM; ++d)
        dotd = fma((double)e[d], (double)xr[d], dotd);
    float M  = (float)dotd;              // one fp32 rounding (sgemm-like)
    float t1 = __fadd_rn(A, nn);         // fp32(A + B_c)
    return __fsub_rn(t1, 2.0f * M);      // 2M exact
}

// ---------------- kernel 1: codebook squared norms (np-exact) ----------------
__global__ void vq_n2(const float* __restrict__ cb, float* __restrict__ n2) {
    int code = blockIdx.x * 256 + threadIdx.x;   // grid = 4 blocks
    n2[code] = np_sumsq_128(cb + (size_t)code * D_DIM);
}

// ---------------- kernel 1b: split codebook into bf16 hi/lo ----------------
__global__ void vq_split(const float* __restrict__ cb, unsigned short* __restrict__ EH,
                         unsigned short* __restrict__ EL) {
    int i = blockIdx.x * 256 + threadIdx.x;      // grid = 512 blocks
    float e = cb[i];
    unsigned short h = bf16_rn(e);
    float fl = e - bf16_to_f(h);                 // exact (Sterbenz)
    EH[i] = h;
    EL[i] = bf16_rn(fl);
}

// ---------------- kernel 2: MFMA scoring + per-row top-3 ----------------
// Codes on M, rows on N. C/D: col=lane&15 -> x-row (fixed per lane),
// row=quad*4+reg -> code. Each wave: 64 rows x all 1024 codes.
// dot via bf16 split: eh*xh + eh*xl + el*xh, fp32 MFMA accum (err ~3e-7).
__launch_bounds__(256, 2)
__global__ void vq_mfma(const float* __restrict__ x,
                        const unsigned short* __restrict__ EH,
                        const unsigned short* __restrict__ EL,
                        const float* __restrict__ n2,
                        unsigned* __restrict__ best_idx,
                        unsigned* __restrict__ work_list,
                        unsigned* __restrict__ work_count) {
    const int lane = threadIdx.x & 63;
    const int wid  = threadIdx.x >> 6;
    const int q    = lane >> 4;          // quad 0..3
    const int col  = lane & 15;
    const int rbase = blockIdx.x * 256 + wid * 64;

    // B operand (x rows), resident: B[k][n]: n = col = row-in-tile, k = q*8+j.
    short8 xh[4][4], xl[4][4];           // [row-tile][kstep] — 128 VGPRs
    #pragma unroll
    for (int r = 0; r < 4; ++r) {
        const float* xrow = x + (size_t)(rbase + 16 * r + col) * D_DIM;
        #pragma unroll
        for (int k = 0; k < 4; ++k) {
            const float* p = xrow + k * 32 + q * 8;
            f32x4 v0 = *(const f32x4*)p;
            f32x4 v1 = *(const f32x4*)(p + 4);
            float f[8] = {v0.x, v0.y, v0.z, v0.w, v1.x, v1.y, v1.z, v1.w};
            short8 h, l;
            #pragma unroll
            for (int j = 0; j < 8; ++j) {
                unsigned short hb = bf16_rn(f[j]);
                float fl = f[j] - bf16_to_f(hb);
                h[j] = (short)hb;
                l[j] = (short)bf16_rn(fl);
            }
            xh[r][k] = h; xl[r][k] = l;
        }
    }

    float b1[4], b2[4], b3[4];
    unsigned i1[4], i2[4];
    #pragma unroll
    for (int r = 0; r < 4; ++r) {
        b1[r] = b2[r] = b3[r] = 3.0e38f;
        i1[r] = i2[r] = 0;
    }

    for (int ct = 0; ct < K_CODES / 16; ++ct) {
        const unsigned short* ph = EH + ((size_t)(ct * 16 + col)) * D_DIM + q * 8;
        const unsigned short* pl = EL + ((size_t)(ct * 16 + col)) * D_DIM + q * 8;

        f32x4 acc[4];
        #pragma unroll
        for (int r = 0; r < 4; ++r) acc[r] = (f32x4){0.f, 0.f, 0.f, 0.f};

        #pragma unroll
        for (int k = 0; k < 4; ++k) {
            short8 eh = *(const short8*)(ph + k * 32);
            short8 el = *(const short8*)(pl + k * 32);
            #pragma unroll
            for (int r = 0; r < 4; ++r) {
                acc[r] = __builtin_amdgcn_mfma_f32_16x16x32_bf16(eh, xh[r][k], acc[r], 0, 0, 0);
                acc[r] = __builtin_amdgcn_mfma_f32_16x16x32_bf16(eh, xl[r][k], acc[r], 0, 0, 0);
                acc[r] = __builtin_amdgcn_mfma_f32_16x16x32_bf16(el, xh[r][k], acc[r], 0, 0, 0);
            }
        }

        f32x4 nn = *(const f32x4*)(n2 + ct * 16 + q * 4);
        #pragma unroll
        for (int r = 0; r < 4; ++r) {
            #pragma unroll
            for (int g = 0; g < 4; ++g) {
                float v = fmaf(-2.0f, acc[r][g], nn[g]);
                unsigned c = (unsigned)(ct * 16 + q * 4 + g);
                bool lt1 = v < b1[r];
                bool lt2 = v < b2[r];
                bool lt3 = v < b3[r];
                b3[r] = lt2 ? b2[r] : (lt3 ? v : b3[r]);
                b2[r] = lt1 ? b1[r] : (lt2 ? v : b2[r]);
                i2[r] = lt1 ? i1[r] : (lt2 ? c : i2[r]);
                b1[r] = lt1 ? v : b1[r];
                i1[r] = lt1 ? c : i1[r];
            }
        }
    }

    // merge sorted top-3 (scores) + top-2 (indices) across the 4 quads
    #pragma unroll
    for (int r = 0; r < 4; ++r) {
        #pragma unroll
        for (int m = 16; m <= 32; m <<= 1) {
            float    oa1 = __shfl_xor(b1[r], m), oa2 = __shfl_xor(b2[r], m), oa3 = __shfl_xor(b3[r], m);
            unsigned oj1 = __shfl_xor(i1[r], m), oj2 = __shfl_xor(i2[r], m);
            // two-pointer merge of sorted triples (first-index on score ties)
            bool t1 = (oa1 < b1[r]) || (oa1 == b1[r] && oj1 < i1[r]);
            float    m1 = t1 ? oa1 : b1[r];
            unsigned w1 = t1 ? oj1 : i1[r];
            float    ha = t1 ? b1[r] : b2[r];   unsigned iha = t1 ? i1[r] : i2[r];
            float    hb = t1 ? oa2   : oa1;     unsigned ihb = t1 ? oj2   : oj1;
            bool t2 = (hb < ha) || (hb == ha && ihb < iha);
            float    m2 = t2 ? hb : ha;
            unsigned w2 = t2 ? ihb : iha;
            float ha2 = t2 ? ha : (t1 ? b2[r] : b3[r]);
            float hb2 = t2 ? (t1 ? oa3 : oa2) : hb;
            float m3 = fminf(ha2, hb2);
            b1[r] = m1; i1[r] = w1; b2[r] = m2; i2[r] = w2; b3[r] = m3;
        }
        if (lane < 16) {
            int row = rbase + 16 * r + lane;
            best_idx[row] = i1[r];
            if (b2[r] - b1[r] < MARGIN) {
                bool full = (b3[r] - b1[r] < MARGIN);
                unsigned p = atomicAdd(work_count, 1u);
                work_list[p] = (unsigned)row | (i2[r] << 17) | (full ? 0x80000000u : 0u);
            }
        }
    }
}

// ---------------- kernel 3a: pair resolve (one lane per flagged row) --------
// Quantized tie is provably between i1 (=best_idx[row]) and i2 only.
__launch_bounds__(256, 1)
__global__ void vq_pair(const float* __restrict__ x, const float* __restrict__ cb,
                        const float* __restrict__ n2,
                        const unsigned* __restrict__ work_count,
                        const unsigned* __restrict__ work_list,
                        unsigned* __restrict__ best_idx) {
    const unsigned gid = blockIdx.x * 256 + threadIdx.x;
    const unsigned n = *work_count;
    for (unsigned p = gid; p < n; p += 65536) {
        unsigned e = work_list[p];
        if (e & 0x80000000u) continue;           // full-rescan rows elsewhere
        unsigned row = e & 0x1FFFFu;
        unsigned c2  = (e >> 17) & 0x3FFu;
        unsigned c1  = best_idx[row];

        float xr[D_DIM];
        #pragma unroll
        for (int i = 0; i < D_DIM / 4; ++i) {
            f32x4 v = ((const f32x4*)(x + (size_t)row * D_DIM))[i];
            xr[4 * i + 0] = v.x; xr[4 * i + 1] = v.y;
            xr[4 * i + 2] = v.z; xr[4 * i + 3] = v.w;
        }
        float A = np_sumsq_128(xr);
        float dq1 = quant_score(cb + (size_t)c1 * D_DIM, xr, A, n2[c1]);
        float dq2 = quant_score(cb + (size_t)c2 * D_DIM, xr, A, n2[c2]);
        // np.argmin: lower score wins; on exact tie, lower index.
        unsigned win = (dq2 < dq1 || (dq2 == dq1 && c2 < c1)) ? c2 : c1;
        best_idx[row] = win;
    }
}

// ---------------- kernel 3b: full rescan (rare: >=3 codes in window) --------
__launch_bounds__(256, 1)
__global__ void vq_full(const float* __restrict__ x, const float* __restrict__ cb,
                        const float* __restrict__ n2,
                        const unsigned* __restrict__ work_count,
                        const unsigned* __restrict__ work_list,
                        unsigned* __restrict__ best_idx) {
    const int lane = threadIdx.x & 63;
    const unsigned gw = blockIdx.x * 4 + (threadIdx.x >> 6);
    const unsigned n = *work_count;
    for (unsigned wi = gw; wi < n; wi += 1024) {
        unsigned e = work_list[wi];
        if (!(e & 0x80000000u)) continue;
        unsigned row = e & 0x1FFFFu;
        const float* xrow = x + (size_t)row * D_DIM;

        float xr[D_DIM];
        #pragma unroll
        for (int i = 0; i < D_DIM / 4; ++i) {
            f32x4 v = ((const f32x4*)xrow)[i];
            xr[4 * i + 0] = v.x; xr[4 * i + 1] = v.y;
            xr[4 * i + 2] = v.z; xr[4 * i + 3] = v.w;
        }
        float A = np_sumsq_128(xr);

        float smin = 3.0e38f;
        #pragma unroll 1
        for (int j = 0; j < K_CODES / 64; ++j) {
            unsigned c = (unsigned)lane * (K_CODES / 64) + j;
            smin = fminf(smin, score_f32(cb + (size_t)c * D_DIM, xr, n2[c]));
        }
        float b1w = smin;
        #pragma unroll
        for (int m = 1; m < 64; m <<= 1) b1w = fminf(b1w, __shfl_xor(b1w, m));

        float bestq = 3.0e38f; unsigned bi = 0xffffffffu;
        #pragma unroll 1
        for (int j = 0; j < K_CODES / 64; ++j) {
            unsigned c = (unsigned)lane * (K_CODES / 64) + j;
            float s = score_f32(cb + (size_t)c * D_DIM, xr, n2[c]);
            if (s < b1w + CAND_MARGIN) {
                float dq = quant_score(cb + (size_t)c * D_DIM, xr, A, n2[c]);
                if (dq < bestq) { bestq = dq; bi = c; }   // strict < = first idx
            }
        }
        #pragma unroll
        for (int m = 1; m < 64; m <<= 1) {
            float    ob = __shfl_xor(bestq, m);
            unsigned oi = __shfl_xor(bi, m);
            if (ob < bestq || (ob == bestq && oi < bi)) { bestq = ob; bi = oi; }
        }
        if (lane == 0) best_idx[row] = bi;
    }
}

// ---------------- kernel 4: gather + straight-through + loss partials --------
__global__ void vq_out(const float* __restrict__ x, const float* __restrict__ cb,
                       const unsigned* __restrict__ best_idx, float* __restrict__ out,
                       double* __restrict__ partials) {
    const int t = threadIdx.x;
    const int rloc = t >> 5;
    const int q = t & 31;
    double lsum = 0.0;
    for (int it = 0; it < N_ROWS / (1024 * 8); ++it) {
        int row = it * (1024 * 8) + blockIdx.x * 8 + rloc;
        unsigned idx = best_idx[row];
        float4 xv = ((const float4*)x)[(size_t)row * 32 + q];
        float4 ev = ((const float4*)cb)[(size_t)idx * 32 + q];
        float dx = ev.x - xv.x, dy = ev.y - xv.y, dz = ev.z - xv.z, dw = ev.w - xv.w;
        float4 o;
        o.x = xv.x + dx; o.y = xv.y + dy; o.z = xv.z + dz; o.w = xv.w + dw;
        ((float4*)out)[(size_t)row * 32 + q] = o;
        lsum += (double)dx * dx + (double)dy * dy + (double)dz * dz + (double)dw * dw;
        if (q == 0) out[(size_t)N_ROWS * D_DIM + 1 + row] = (float)idx;
    }
    #pragma unroll
    for (int m = 32; m >= 1; m >>= 1) lsum += __shfl_xor(lsum, m);
    __shared__ double wsum[4];
    if ((t & 63) == 0) wsum[t >> 6] = lsum;
    __syncthreads();
    if (t == 0) partials[blockIdx.x] = wsum[0] + wsum[1] + wsum[2] + wsum[3];
}

// ---------------- kernel 5: finalize loss ----------------
__global__ void vq_fin(const double* __restrict__ partials, float* __restrict__ out) {
    int t = threadIdx.x;
    double s = partials[t] + partials[t + 256] + partials[t + 512] + partials[t + 768];
    #pragma unroll
    for (int m = 32; m >= 1; m >>= 1) s += __shfl_xor(s, m);
    __shared__ double wsum[4];
    if ((t & 63) == 0) wsum[t >> 6] = s;
    __syncthreads();
    if (t == 0) {
        double total = wsum[0] + wsum[1] + wsum[2] + wsum[3];
        out[(size_t)N_ROWS * D_DIM] = (float)(1.25 * total / ((double)N_ROWS * D_DIM));
    }
}

extern "C" void kernel_launch(void* const* d_in, const int* in_sizes, int n_in,
                              void* d_out, int out_size, void* d_ws, size_t ws_size,
                              hipStream_t stream) {
    const float* x  = (const float*)d_in[0];
    const float* cb = (const float*)d_in[1];
    float* out = (float*)d_out;
    char* ws = (char*)d_ws;

    unsigned*       work_count = (unsigned*)ws;
    float*          n2         = (float*)(ws + 1024);
    unsigned*       best_idx   = (unsigned*)(ws + 8192);
    unsigned*       work_list  = (unsigned*)(ws + 8192 + 524288);
    double*         partials   = (double*)(ws + 8192 + 2 * 524288);
    unsigned short* EH         = (unsigned short*)(ws + 1064960);
    unsigned short* EL         = (unsigned short*)(ws + 1327104);

    hipMemsetAsync(ws, 0, 1024, stream);  // work_count = 0
    vq_n2    <<<K_CODES / 256, 256, 0, stream>>>(cb, n2);
    vq_split <<<K_CODES * D_DIM / 256, 256, 0, stream>>>(cb, EH, EL);
    vq_mfma  <<<N_ROWS / 256, 256, 0, stream>>>(x, EH, EL, n2, best_idx, work_list, work_count);
    vq_pair  <<<256, 256, 0, stream>>>(x, cb, n2, work_count, work_list, best_idx);
    vq_full  <<<256, 256, 0, stream>>>(x, cb, n2, work_count, work_list, best_idx);
    vq_out   <<<1024, 256, 0, stream>>>(x, cb, best_idx, out, partials);
    vq_fin   <<<1, 256, 0, stream>>>(partials, out);
}